// Round 14
// baseline (684.164 us; speedup 1.0000x reference)
//
#include <hip/hip_runtime.h>
#include <hip/hip_bf16.h>

typedef __attribute__((ext_vector_type(8))) short short8;   // 8 bf16
typedef __attribute__((ext_vector_type(4))) float f32x4;
typedef __attribute__((ext_vector_type(16))) float f32x16;
typedef __attribute__((ext_vector_type(4))) unsigned int u32x4;
typedef unsigned int u32;
typedef unsigned short u16;

#define C_ 256
#define G_ 32
#define ND_ 18432          // D*H*W per batch
#define HW_ 2304           // 48*48
#define EPS_ 1e-5f
// (C/8)^-0.5 * log2(e): softmax scale pre-folded with exp2 conversion
#define QS2_ 0.25503487f

static __device__ __forceinline__ u16 f2bf(float f) {
  __hip_bfloat16 h = __float2bfloat16(f);
  return __builtin_bit_cast(u16, h);
}

static __device__ __forceinline__ void gll16(const void* g, void* l) {
  __builtin_amdgcn_global_load_lds(
      (const __attribute__((address_space(1))) unsigned int*)g,
      (__attribute__((address_space(3))) unsigned int*)l, 16, 0, 0);
}

// ---------------- weights f32 -> bf16 (+ zero gn partial accumulators) ----------------
__global__ void k_convert_w(const float* __restrict__ qkv_w,
                            const float* __restrict__ proj_w,
                            u16* __restrict__ wout,
                            float* __restrict__ raw) {
  if (blockIdx.x == 0 && threadIdx.x < 128) raw[threadIdx.x] = 0.f;
  int i = blockIdx.x * 256 + threadIdx.x;   // grid 1024 -> 262144 exactly
  if (i < 196608) wout[i] = f2bf(qkv_w[i]);
  else            wout[i] = f2bf(proj_w[i - 196608]);
}

// ---------------- GroupNorm stats, stage 1: 256 blocks of partial sums ----------------
__global__ __launch_bounds__(256) void k_gn_part(const float* __restrict__ x,
                                                 float* __restrict__ raw) {
  int grp = blockIdx.x >> 2, sub = blockIdx.x & 3;
  const float4* p = (const float4*)(x + (size_t)grp * 147456 + sub * 36864);
  float s1 = 0.f, s2 = 0.f;
  for (int i = threadIdx.x; i < 9216; i += 256) {
    float4 v = p[i];
    s1 += v.x + v.y + v.z + v.w;
    s2 += v.x*v.x + v.y*v.y + v.z*v.z + v.w*v.w;
  }
  for (int off = 1; off < 64; off <<= 1) {
    s1 += __shfl_xor(s1, off, 64);
    s2 += __shfl_xor(s2, off, 64);
  }
  __shared__ float a1[4], a2[4];
  int w = threadIdx.x >> 6;
  if ((threadIdx.x & 63) == 0) { a1[w] = s1; a2[w] = s2; }
  __syncthreads();
  if (threadIdx.x == 0) {
    float t1 = a1[0] + a1[1] + a1[2] + a1[3];
    float t2 = a2[0] + a2[1] + a2[2] + a2[3];
    atomicAdd(&raw[grp * 2], t1);
    atomicAdd(&raw[grp * 2 + 1], t2);
  }
}

// ---------------- GroupNorm stats, stage 2: finalize ----------------
__global__ void k_gn_fin(const float* __restrict__ raw, float* __restrict__ stats) {
  int g = threadIdx.x;
  if (g < 64) {
    float mu  = raw[g * 2] / 147456.0f;
    float var = raw[g * 2 + 1] / 147456.0f - mu * mu;
    stats[g * 2]     = mu;
    stats[g * 2 + 1] = rsqrtf(var + EPS_);
  }
}

// ---------------- normalize + transpose: x[b][c][n] f32 -> h_t[b][n][c] bf16 ----------------
__global__ __launch_bounds__(256) void k_tnorm(const float* __restrict__ x,
                                               const float* __restrict__ stats,
                                               const float* __restrict__ nw,
                                               const float* __restrict__ nb,
                                               u16* __restrict__ h_t) {
  __shared__ u16 tl[64 * 66];
  int wg = blockIdx.x;          // 2304 = b(2) * ct(4) * nt(288)
  int nt = wg % 288; int ct = (wg / 288) & 3; int b = wg / 1152;
  int c0 = ct * 64, n0 = nt * 64;
  int tid = threadIdx.x;
#pragma unroll
  for (int p = 0; p < 4; p++) {
    int c_l = p * 16 + (tid >> 4);
    int n4  = (tid & 15) * 4;
    int cg  = c0 + c_l;
    float4 v = *(const float4*)(x + ((size_t)(b * C_ + cg)) * ND_ + n0 + n4);
    float mu = stats[(b * G_ + (cg >> 3)) * 2];
    float rs = stats[(b * G_ + (cg >> 3)) * 2 + 1];
    float w = nw[cg], bia = nb[cg];
    tl[(n4 + 0) * 66 + c_l] = f2bf((v.x - mu) * rs * w + bia);
    tl[(n4 + 1) * 66 + c_l] = f2bf((v.y - mu) * rs * w + bia);
    tl[(n4 + 2) * 66 + c_l] = f2bf((v.z - mu) * rs * w + bia);
    tl[(n4 + 3) * 66 + c_l] = f2bf((v.w - mu) * rs * w + bia);
  }
  __syncthreads();
#pragma unroll
  for (int p = 0; p < 2; p++) {
    int idx = p * 256 + tid;
    int n_l = idx >> 3, c8 = idx & 7;
    const u32* s = (const u32*)((const char*)tl + n_l * 132 + c8 * 16);
    uint4 vv; vv.x = s[0]; vv.y = s[1]; vv.z = s[2]; vv.w = s[3];
    *(uint4*)(h_t + ((size_t)(b * ND_ + n0 + n_l)) * C_ + c0 + c8 * 8) = vv;
  }
}

// ---------------- QK GEMM (swapped: A=H [n x c], B=W^T [c x o]) ----------------
// Q -> q_ws [b][n][256] (prescaled); K -> k_ws fragment-linear:
// off_u16(slice, t, key, ch) = ((slice*48+t)*1536 + (ch>>3)*48 + key)*8 + (ch&7)
__global__ __launch_bounds__(256) void k_qk(const u16* __restrict__ h_t,
                                            const u16* __restrict__ w_qkv,
                                            const float* __restrict__ qkv_b,
                                            u16* __restrict__ q_ws,
                                            u16* __restrict__ k_ws) {
  int wg = blockIdx.x;
  int nt = wg % 288; int ot = (wg / 288) & 3; int b = wg / 1152;
  int n0 = nt * 64, o0 = ot * 128;
  int lane = threadIdx.x & 63; int w = threadIdx.x >> 6;
  int g = lane >> 4, lid = lane & 15;
  int n_w = n0 + w * 16;
  f32x4 acc[8];
#pragma unroll
  for (int t = 0; t < 8; t++) acc[t] = (f32x4){0.f, 0.f, 0.f, 0.f};
  const short8* Ab = (const short8*)(h_t + ((size_t)(b * ND_ + n_w + lid)) * C_ + g * 8);
#pragma unroll
  for (int ks = 0; ks < 8; ks++) {
    short8 a = Ab[ks * 4];
#pragma unroll
    for (int t = 0; t < 8; t++) {
      short8 bf = *(const short8*)(w_qkv + ((size_t)(o0 + t * 16 + lid)) * C_ + ks * 32 + g * 8);
      acc[t] = __builtin_amdgcn_mfma_f32_16x16x32_bf16(a, bf, acc[t], 0, 0, 0);
    }
  }
  if (o0 < 256) {   // Q path (uniform per block)
#pragma unroll
    for (int t = 0; t < 8; t++) {
      int o_t = o0 + t * 16;
      float bias = qkv_b[o_t + lid];
#pragma unroll
      for (int r = 0; r < 4; r++) {
        int n_idx = n_w + g * 4 + r;
        q_ws[((size_t)(b * ND_ + n_idx)) * C_ + o_t + lid] = f2bf((acc[t][r] + bias) * QS2_);
      }
    }
  } else {          // K path -> fragment-linear layout
#pragma unroll
    for (int t = 0; t < 8; t++) {
      int o_t = o0 + t * 16;
      float bias = qkv_b[o_t + lid];
      int oc = o_t - 256 + lid;
#pragma unroll
      for (int r = 0; r < 4; r++) {
        int n_idx = n_w + g * 4 + r;
        int dd = n_idx / 2304, hw = n_idx % 2304;
        int tt = hw / 48, kk = hw % 48;
        size_t off = ((size_t)((b * 8 + dd) * 48 + tt) * 1536 + (oc >> 3) * 48 + kk) * 8 + (oc & 7);
        k_ws[off] = f2bf(acc[t][r] + bias);
      }
    }
  }
}

// ---------------- V GEMM -> v_ws group-major [slice][grp48][slot6][c256][8] ----------------
__global__ __launch_bounds__(256) void k_v(const u16* __restrict__ h_t,
                                           const u16* __restrict__ w_qkv,
                                           const float* __restrict__ qkv_b,
                                           u16* __restrict__ v_ws) {
  int wg = blockIdx.x;
  int nt = wg % 144; int ot = (wg / 144) & 3; int b = wg / 576;
  int n0 = nt * 128, o0 = ot * 64;
  int lane = threadIdx.x & 63; int w = threadIdx.x >> 6;
  int g = lane >> 4, lid = lane & 15;
  int o_w = o0 + w * 16;
  f32x4 acc[8];
#pragma unroll
  for (int t = 0; t < 8; t++) acc[t] = (f32x4){0.f, 0.f, 0.f, 0.f};
  const short8* Ab = (const short8*)(w_qkv + ((size_t)(512 + o_w + lid)) * C_ + g * 8);
#pragma unroll
  for (int ks = 0; ks < 8; ks++) {
    short8 a = Ab[ks * 4];
#pragma unroll
    for (int t = 0; t < 8; t++) {
      short8 bf = *(const short8*)(h_t + ((size_t)(b * ND_ + n0 + t * 16 + lid)) * C_ + ks * 32 + g * 8);
      acc[t] = __builtin_amdgcn_mfma_f32_16x16x32_bf16(a, bf, acc[t], 0, 0, 0);
    }
  }
#pragma unroll
  for (int t = 0; t < 8; t++) {
#pragma unroll
    for (int r = 0; r < 4; r++) {
      int o = o_w + g * 4 + r;
      int n = n0 + t * 16 + lid;
      int d = n / 2304; int hw = n % 2304;
      int grp = hw / 48; int j = hw % 48;
      size_t idx = ((size_t)(((b * 8 + d) * 48 + grp) * 6 + (j >> 3))) * 2048 + o * 8 + (j & 7);
      v_ws[idx] = f2bf(acc[t][r] + qkv_b[512 + o]);
    }
  }
}

// ---------------- fused attention: 288 blocks x 4 waves x 32q (128 q shared tiles) ----------------
// R8 structure (best known: LDS-port-bound). One change: QK's k1 read aliases the
// 16 garbage rows (keys 48..63, discarded) onto the real rows 32..47 via (l31&15) --
// same-address lanes broadcast for free, cutting unique QK LDS reads 32->20 KB/wave/iter
// (block 272->224 KB/iter, -18%). Plus T5 setprio around MFMA clusters (2 blocks/CU
// on the doubled CUs = real wave-role diversity).
// Schedule: STG_K(t+1) -> QK -> softmax -> vmcnt(0)+bar -> PV -> bar -> STG_V(t+1).
__global__ __launch_bounds__(256, 2) void k_attn(const u16* __restrict__ q_ws,
                                                 const u16* __restrict__ k_ws,
                                                 const u16* __restrict__ v_ws,
                                                 u16* __restrict__ ao) {
  // [kb0 24576][kb1 24576][V 24576][guard 512]
  __shared__ __align__(16) unsigned char lds[74240];
  int wg = blockIdx.x;
  int virt = (wg & 7) * 36 + (wg >> 3);   // XCD-affine: 288 = 8 * 36
  int slice = virt / 18;                  // 0..15
  int qt = virt % 18;                     // 0..17 (128 q each)
  int b = slice >> 3, d = slice & 7;
  int tid = threadIdx.x;
  int lane = tid & 63, w = tid >> 6;
  int l31 = lane & 31, hi = lane >> 5;

  const char* kgb = (const char*)k_ws + (size_t)slice * 1179648;
  const char* vgb = (const char*)v_ws + (size_t)slice * 1179648;

  // hoist Q fragments (32 q per wave; prescaled by softmax-scale*log2e)
  size_t nbase = (size_t)b * ND_ + d * HW_ + qt * 128 + w * 32;
  const char* qp = (const char*)q_ws + (nbase + l31) * 512 + hi * 16;
  short8 qf[16];
#pragma unroll
  for (int ks = 0; ks < 16; ks++) qf[ks] = *(const short8*)(qp + ks * 32);

  f32x16 acc[8];
#pragma unroll
  for (int i = 0; i < 8; i++) acc[i] = (f32x16)0.0f;

  // stage K tile t into kb base_: 256 thr x 16B x 6, linear both sides
#define STG_K(t_, base_) {                                             \
    const char* s_ = kgb + (size_t)(t_) * 24576 + tid * 16;            \
    char* d_ = (char*)lds + (base_) + w * 1024;                        \
    _Pragma("unroll")                                                  \
    for (int i_ = 0; i_ < 6; i_++)                                     \
      gll16(s_ + i_ * 4096, d_ + i_ * 4096);                           \
  }
  // stage V tile t into the single V buffer @49152
#define STG_V(t_) {                                                    \
    const char* s_ = vgb + (size_t)(t_) * 24576 + tid * 16;            \
    char* d_ = (char*)lds + 49152 + w * 1024;                          \
    _Pragma("unroll")                                                  \
    for (int i_ = 0; i_ < 6; i_++)                                     \
      gll16(s_ + i_ * 4096, d_ + i_ * 4096);                           \
  }

  STG_K(0, 0);
  STG_V(0);
  __builtin_amdgcn_sched_barrier(0);
  asm volatile("s_waitcnt vmcnt(0)" ::: "memory");
  __builtin_amdgcn_sched_barrier(0);
  __builtin_amdgcn_s_barrier();

  int kcur = 0;
  for (int t = 0; t < 48; t++) {
    if (t < 47) STG_K(t + 1, (kcur ^ 1) * 24576);   // fire; drains at mid-iter wait

    const char* kb = (const char*)lds + kcur * 24576;

    // QK^T swapped: S[key][q], K fragment-linear: slot*768 + key*16.
    // k1: keys 32..47 real; rows 48..63 aliased onto 32..47 (broadcast, free).
    f32x16 S0 = (f32x16)0.0f, S1 = (f32x16)0.0f;
    __builtin_amdgcn_s_setprio(1);
#pragma unroll
    for (int ks = 0; ks < 16; ks++) {
      const char* p = kb + (ks * 2 + hi) * 768;
      short8 k0 = *(const short8*)(p + l31 * 16);
      short8 k1 = *(const short8*)(p + 512 + (l31 & 15) * 16);  // dedup'd garbage rows
      S0 = __builtin_amdgcn_mfma_f32_32x32x16_bf16(k0, qf[ks], S0, 0, 0, 0);
      S1 = __builtin_amdgcn_mfma_f32_32x32x16_bf16(k1, qf[ks], S1, 0, 0, 0);
    }
    __builtin_amdgcn_s_setprio(0);

    // exact softmax over the 48 keys (one group), lane-local + one half-swap
#pragma unroll
    for (int r = 0; r < 16; r++) S0[r] = __builtin_amdgcn_exp2f(S0[r]);
#pragma unroll
    for (int r = 0; r < 8; r++)  S1[r] = __builtin_amdgcn_exp2f(S1[r]);
    float z = 0.f;
#pragma unroll
    for (int r = 0; r < 16; r++) z += S0[r];
#pragma unroll
    for (int r = 0; r < 8; r++)  z += S1[r];
    z += __shfl_xor(z, 32, 64);
    float inv = __builtin_amdgcn_rcpf(z);
#pragma unroll
    for (int r = 0; r < 16; r++) S0[r] *= inv;
#pragma unroll
    for (int r = 0; r < 8; r++)  S1[r] *= inv;

    // pack P -> PV A-fragments (cvt_pk + permlane32_swap)
    short8 pa[3];
#pragma unroll
    for (int s = 0; s < 3; s++) {
      const f32x16& P = (s < 2) ? S0 : S1;
      const int a = (s == 1) ? 8 : 0;
      u32 u0, u1, v0, v1;
      asm("v_cvt_pk_bf16_f32 %0, %1, %2" : "=v"(u0) : "v"(P[a + 0]), "v"(P[a + 1]));
      asm("v_cvt_pk_bf16_f32 %0, %1, %2" : "=v"(u1) : "v"(P[a + 2]), "v"(P[a + 3]));
      asm("v_cvt_pk_bf16_f32 %0, %1, %2" : "=v"(v0) : "v"(P[a + 4]), "v"(P[a + 5]));
      asm("v_cvt_pk_bf16_f32 %0, %1, %2" : "=v"(v1) : "v"(P[a + 6]), "v"(P[a + 7]));
      asm("v_permlane32_swap_b32 %0, %1" : "+v"(u0), "+v"(v0));
      asm("v_permlane32_swap_b32 %0, %1" : "+v"(u1), "+v"(v1));
      u32x4 wv; wv[0] = u0; wv[1] = u1; wv[2] = v0; wv[3] = v1;
      pa[s] = __builtin_bit_cast(short8, wv);
    }

    // mid sync: K(t+1) and V(t) landed (own loads), then cross-wave barrier
    __builtin_amdgcn_sched_barrier(0);
    asm volatile("s_waitcnt vmcnt(0)" ::: "memory");
    __builtin_amdgcn_sched_barrier(0);
    __builtin_amdgcn_s_barrier();

    // PV from LDS: V fragment-linear: slot*4096 + c*16
    const char* vb = (const char*)lds + 49152;
    __builtin_amdgcn_s_setprio(1);
#pragma unroll
    for (int s = 0; s < 3; s++) {
      const char* vs = vb + (s * 2 + hi) * 4096 + l31 * 16;
#pragma unroll
      for (int ct = 0; ct < 8; ct++) {
        short8 vf = *(const short8*)(vs + ct * 512);
        acc[ct] = __builtin_amdgcn_mfma_f32_32x32x16_bf16(pa[s], vf, acc[ct], 0, 0, 0);
      }
    }
    __builtin_amdgcn_s_setprio(0);

    // all waves done reading V buffer, then refill it for t+1
    __builtin_amdgcn_s_barrier();
    if (t < 47) STG_V(t + 1);
    kcur ^= 1;
  }

  // epilogue: D layout col(l31)=c, row=(r&3)+8*(r>>2)+4*hi = q
#pragma unroll
  for (int ct = 0; ct < 8; ct++) {
#pragma unroll
    for (int r = 0; r < 16; r++) {
      int ql = (r & 3) + 8 * (r >> 2) + 4 * hi;
      ao[(nbase + ql) * 256 + ct * 32 + l31] = f2bf(acc[ct][r]);
    }
  }
}

// ---------------- proj + bias + residual -> d_out f32 channel-major ----------------
__global__ __launch_bounds__(256) void k_proj(const u16* __restrict__ ao,
                                              const u16* __restrict__ w_p,
                                              const float* __restrict__ proj_b,
                                              const float* __restrict__ x,
                                              float* __restrict__ out) {
  int wg = blockIdx.x;
  int nt = wg % 144; int ot = (wg / 144) & 3; int b = wg / 576;
  int n0 = nt * 128, o0 = ot * 64;
  int lane = threadIdx.x & 63; int w = threadIdx.x >> 6;
  int g = lane >> 4, lid = lane & 15;
  int o_w = o0 + w * 16;
  f32x4 acc[8];
#pragma unroll
  for (int t = 0; t < 8; t++) acc[t] = (f32x4){0.f, 0.f, 0.f, 0.f};
  const short8* Ab = (const short8*)(w_p + ((size_t)(o_w + lid)) * C_ + g * 8);
#pragma unroll
  for (int ks = 0; ks < 8; ks++) {
    short8 a = Ab[ks * 4];
#pragma unroll
    for (int t = 0; t < 8; t++) {
      short8 bf = *(const short8*)(ao + ((size_t)(b * ND_ + n0 + t * 16 + lid)) * C_ + ks * 32 + g * 8);
      acc[t] = __builtin_amdgcn_mfma_f32_16x16x32_bf16(a, bf, acc[t], 0, 0, 0);
    }
  }
#pragma unroll
  for (int t = 0; t < 8; t++) {
#pragma unroll
    for (int r = 0; r < 4; r++) {
      int o = o_w + g * 4 + r;
      size_t off = ((size_t)(b * C_ + o)) * ND_ + n0 + t * 16 + lid;
      out[off] = acc[t][r] + proj_b[o] + x[off];
    }
  }
}

extern "C" void kernel_launch(void* const* d_in, const int* in_sizes, int n_in,
                              void* d_out, int out_size, void* d_ws, size_t ws_size,
                              hipStream_t stream) {
  const float* x      = (const float*)d_in[0];
  const float* norm_w = (const float*)d_in[1];
  const float* norm_b = (const float*)d_in[2];
  const float* qkv_w  = (const float*)d_in[3];
  const float* qkv_b  = (const float*)d_in[4];
  const float* proj_w = (const float*)d_in[5];
  const float* proj_b = (const float*)d_in[6];

  char* ws = (char*)d_ws;
  float* stats = (float*)ws;            // f32[128]
  float* raw   = (float*)(ws + 512);    // f32[128] partial accumulators
  u16* w_qkv = (u16*)(ws + 1024);
  u16* w_p   = (u16*)(ws + 1024 + 393216);
  u16* h_t   = (u16*)(ws + 525312);
  u16* q_ws  = h_t + 9437184;
  u16* k_ws  = q_ws + 9437184;
  u16* v_ws  = k_ws + 9437184;
  u16* ao    = h_t;  // alias: h_t dead after k_v
  float* out = (float*)d_out;

  if (ws_size < (size_t)525312 + 4ull * 9437184ull * 2ull) return;

  hipLaunchKernelGGL(k_convert_w, dim3(1024), dim3(256), 0, stream, qkv_w, proj_w, w_qkv, raw);
  hipLaunchKernelGGL(k_gn_part,   dim3(256),  dim3(256), 0, stream, x, raw);
  hipLaunchKernelGGL(k_gn_fin,    dim3(1),    dim3(64),  0, stream, raw, stats);
  hipLaunchKernelGGL(k_tnorm,     dim3(2304), dim3(256), 0, stream, x, stats, norm_w, norm_b, h_t);
  hipLaunchKernelGGL(k_qk,        dim3(2304), dim3(256), 0, stream, h_t, w_qkv, qkv_b, q_ws, k_ws);
  hipLaunchKernelGGL(k_v,         dim3(1152), dim3(256), 0, stream, h_t, w_qkv, qkv_b, v_ws);
  hipLaunchKernelGGL(k_attn,      dim3(288),  dim3(256), 0, stream, q_ws, k_ws, v_ws, ao);
  hipLaunchKernelGGL(k_proj,      dim3(1152), dim3(256), 0, stream, ao, w_p, proj_b, x, out);
}

// Round 15
// 334.411 us; speedup vs baseline: 2.0459x; 2.0459x over previous
//
#include <hip/hip_runtime.h>
#include <hip/hip_bf16.h>

typedef __attribute__((ext_vector_type(8))) short short8;   // 8 bf16
typedef __attribute__((ext_vector_type(4))) float f32x4;
typedef __attribute__((ext_vector_type(16))) float f32x16;
typedef __attribute__((ext_vector_type(4))) unsigned int u32x4;
typedef unsigned int u32;
typedef unsigned short u16;

#define C_ 256
#define G_ 32
#define ND_ 18432          // D*H*W per batch
#define HW_ 2304           // 48*48
#define EPS_ 1e-5f
// (C/8)^-0.5 * log2(e): softmax scale pre-folded with exp2 conversion
#define QS2_ 0.25503487f

static __device__ __forceinline__ u16 f2bf(float f) {
  __hip_bfloat16 h = __float2bfloat16(f);
  return __builtin_bit_cast(u16, h);
}

static __device__ __forceinline__ void gll16(const void* g, void* l) {
  __builtin_amdgcn_global_load_lds(
      (const __attribute__((address_space(1))) unsigned int*)g,
      (__attribute__((address_space(3))) unsigned int*)l, 16, 0, 0);
}

// ---------------- weights f32 -> bf16 (+ zero gn partial accumulators) ----------------
__global__ void k_convert_w(const float* __restrict__ qkv_w,
                            const float* __restrict__ proj_w,
                            u16* __restrict__ wout,
                            float* __restrict__ raw) {
  if (blockIdx.x == 0 && threadIdx.x < 128) raw[threadIdx.x] = 0.f;
  int i = blockIdx.x * 256 + threadIdx.x;   // grid 1024 -> 262144 exactly
  if (i < 196608) wout[i] = f2bf(qkv_w[i]);
  else            wout[i] = f2bf(proj_w[i - 196608]);
}

// ---------------- GroupNorm stats, stage 1: 256 blocks of partial sums ----------------
__global__ __launch_bounds__(256) void k_gn_part(const float* __restrict__ x,
                                                 float* __restrict__ raw) {
  int grp = blockIdx.x >> 2, sub = blockIdx.x & 3;
  const float4* p = (const float4*)(x + (size_t)grp * 147456 + sub * 36864);
  float s1 = 0.f, s2 = 0.f;
  for (int i = threadIdx.x; i < 9216; i += 256) {
    float4 v = p[i];
    s1 += v.x + v.y + v.z + v.w;
    s2 += v.x*v.x + v.y*v.y + v.z*v.z + v.w*v.w;
  }
  for (int off = 1; off < 64; off <<= 1) {
    s1 += __shfl_xor(s1, off, 64);
    s2 += __shfl_xor(s2, off, 64);
  }
  __shared__ float a1[4], a2[4];
  int w = threadIdx.x >> 6;
  if ((threadIdx.x & 63) == 0) { a1[w] = s1; a2[w] = s2; }
  __syncthreads();
  if (threadIdx.x == 0) {
    float t1 = a1[0] + a1[1] + a1[2] + a1[3];
    float t2 = a2[0] + a2[1] + a2[2] + a2[3];
    atomicAdd(&raw[grp * 2], t1);
    atomicAdd(&raw[grp * 2 + 1], t2);
  }
}

// ---------------- GroupNorm stats, stage 2: finalize ----------------
__global__ void k_gn_fin(const float* __restrict__ raw, float* __restrict__ stats) {
  int g = threadIdx.x;
  if (g < 64) {
    float mu  = raw[g * 2] / 147456.0f;
    float var = raw[g * 2 + 1] / 147456.0f - mu * mu;
    stats[g * 2]     = mu;
    stats[g * 2 + 1] = rsqrtf(var + EPS_);
  }
}

// ---------------- normalize + transpose: x[b][c][n] f32 -> h_t[b][n][c] bf16 ----------------
__global__ __launch_bounds__(256) void k_tnorm(const float* __restrict__ x,
                                               const float* __restrict__ stats,
                                               const float* __restrict__ nw,
                                               const float* __restrict__ nb,
                                               u16* __restrict__ h_t) {
  __shared__ u16 tl[64 * 66];
  int wg = blockIdx.x;          // 2304 = b(2) * ct(4) * nt(288)
  int nt = wg % 288; int ct = (wg / 288) & 3; int b = wg / 1152;
  int c0 = ct * 64, n0 = nt * 64;
  int tid = threadIdx.x;
#pragma unroll
  for (int p = 0; p < 4; p++) {
    int c_l = p * 16 + (tid >> 4);
    int n4  = (tid & 15) * 4;
    int cg  = c0 + c_l;
    float4 v = *(const float4*)(x + ((size_t)(b * C_ + cg)) * ND_ + n0 + n4);
    float mu = stats[(b * G_ + (cg >> 3)) * 2];
    float rs = stats[(b * G_ + (cg >> 3)) * 2 + 1];
    float w = nw[cg], bia = nb[cg];
    tl[(n4 + 0) * 66 + c_l] = f2bf((v.x - mu) * rs * w + bia);
    tl[(n4 + 1) * 66 + c_l] = f2bf((v.y - mu) * rs * w + bia);
    tl[(n4 + 2) * 66 + c_l] = f2bf((v.z - mu) * rs * w + bia);
    tl[(n4 + 3) * 66 + c_l] = f2bf((v.w - mu) * rs * w + bia);
  }
  __syncthreads();
#pragma unroll
  for (int p = 0; p < 2; p++) {
    int idx = p * 256 + tid;
    int n_l = idx >> 3, c8 = idx & 7;
    const u32* s = (const u32*)((const char*)tl + n_l * 132 + c8 * 16);
    uint4 vv; vv.x = s[0]; vv.y = s[1]; vv.z = s[2]; vv.w = s[3];
    *(uint4*)(h_t + ((size_t)(b * ND_ + n0 + n_l)) * C_ + c0 + c8 * 8) = vv;
  }
}

// ---------------- QK GEMM (swapped: A=H [n x c], B=W^T [c x o]) ----------------
// Q -> q_ws [b][n][256] (prescaled); K -> k_ws fragment-linear:
// off_u16(slice, t, key, ch) = ((slice*48+t)*1536 + (ch>>3)*48 + key)*8 + (ch&7)
__global__ __launch_bounds__(256) void k_qk(const u16* __restrict__ h_t,
                                            const u16* __restrict__ w_qkv,
                                            const float* __restrict__ qkv_b,
                                            u16* __restrict__ q_ws,
                                            u16* __restrict__ k_ws) {
  int wg = blockIdx.x;
  int nt = wg % 288; int ot = (wg / 288) & 3; int b = wg / 1152;
  int n0 = nt * 64, o0 = ot * 128;
  int lane = threadIdx.x & 63; int w = threadIdx.x >> 6;
  int g = lane >> 4, lid = lane & 15;
  int n_w = n0 + w * 16;
  f32x4 acc[8];
#pragma unroll
  for (int t = 0; t < 8; t++) acc[t] = (f32x4){0.f, 0.f, 0.f, 0.f};
  const short8* Ab = (const short8*)(h_t + ((size_t)(b * ND_ + n_w + lid)) * C_ + g * 8);
#pragma unroll
  for (int ks = 0; ks < 8; ks++) {
    short8 a = Ab[ks * 4];
#pragma unroll
    for (int t = 0; t < 8; t++) {
      short8 bf = *(const short8*)(w_qkv + ((size_t)(o0 + t * 16 + lid)) * C_ + ks * 32 + g * 8);
      acc[t] = __builtin_amdgcn_mfma_f32_16x16x32_bf16(a, bf, acc[t], 0, 0, 0);
    }
  }
  if (o0 < 256) {   // Q path (uniform per block)
#pragma unroll
    for (int t = 0; t < 8; t++) {
      int o_t = o0 + t * 16;
      float bias = qkv_b[o_t + lid];
#pragma unroll
      for (int r = 0; r < 4; r++) {
        int n_idx = n_w + g * 4 + r;
        q_ws[((size_t)(b * ND_ + n_idx)) * C_ + o_t + lid] = f2bf((acc[t][r] + bias) * QS2_);
      }
    }
  } else {          // K path -> fragment-linear layout
#pragma unroll
    for (int t = 0; t < 8; t++) {
      int o_t = o0 + t * 16;
      float bias = qkv_b[o_t + lid];
      int oc = o_t - 256 + lid;
#pragma unroll
      for (int r = 0; r < 4; r++) {
        int n_idx = n_w + g * 4 + r;
        int dd = n_idx / 2304, hw = n_idx % 2304;
        int tt = hw / 48, kk = hw % 48;
        size_t off = ((size_t)((b * 8 + dd) * 48 + tt) * 1536 + (oc >> 3) * 48 + kk) * 8 + (oc & 7);
        k_ws[off] = f2bf(acc[t][r] + bias);
      }
    }
  }
}

// ---------------- V GEMM -> v_ws group-major [slice][grp48][slot6][c256][8] ----------------
__global__ __launch_bounds__(256) void k_v(const u16* __restrict__ h_t,
                                           const u16* __restrict__ w_qkv,
                                           const float* __restrict__ qkv_b,
                                           u16* __restrict__ v_ws) {
  int wg = blockIdx.x;
  int nt = wg % 144; int ot = (wg / 144) & 3; int b = wg / 576;
  int n0 = nt * 128, o0 = ot * 64;
  int lane = threadIdx.x & 63; int w = threadIdx.x >> 6;
  int g = lane >> 4, lid = lane & 15;
  int o_w = o0 + w * 16;
  f32x4 acc[8];
#pragma unroll
  for (int t = 0; t < 8; t++) acc[t] = (f32x4){0.f, 0.f, 0.f, 0.f};
  const short8* Ab = (const short8*)(w_qkv + ((size_t)(512 + o_w + lid)) * C_ + g * 8);
#pragma unroll
  for (int ks = 0; ks < 8; ks++) {
    short8 a = Ab[ks * 4];
#pragma unroll
    for (int t = 0; t < 8; t++) {
      short8 bf = *(const short8*)(h_t + ((size_t)(b * ND_ + n0 + t * 16 + lid)) * C_ + ks * 32 + g * 8);
      acc[t] = __builtin_amdgcn_mfma_f32_16x16x32_bf16(a, bf, acc[t], 0, 0, 0);
    }
  }
#pragma unroll
  for (int t = 0; t < 8; t++) {
#pragma unroll
    for (int r = 0; r < 4; r++) {
      int o = o_w + g * 4 + r;
      int n = n0 + t * 16 + lid;
      int d = n / 2304; int hw = n % 2304;
      int grp = hw / 48; int j = hw % 48;
      size_t idx = ((size_t)(((b * 8 + d) * 48 + grp) * 6 + (j >> 3))) * 2048 + o * 8 + (j & 7);
      v_ws[idx] = f2bf(acc[t][r] + qkv_b[512 + o]);
    }
  }
}

// ---------------- fused attention: 288 blocks x 4 waves x 32q (128 q shared tiles) ----------------
// R8 structure (best known: LDS-port-bound). SINGLE change vs R8: k1's 16 garbage rows
// (keys 48..63, discarded) are aliased onto the real rows 32..47 via (l31&15), expressed
// as TWO loop-invariant base pointers with compile-time ks offsets so the ds_reads stay
// base+offset:imm (2 address VGPRs, no regalloc pressure). Same-address lanes broadcast
// free -> QK LDS traffic 128->96 KB/blk-iter (-12% of the LDS-port wall). No setprio.
// Schedule: STG_K(t+1) -> QK -> softmax -> vmcnt(0)+bar -> PV -> bar -> STG_V(t+1).
__global__ __launch_bounds__(256, 2) void k_attn(const u16* __restrict__ q_ws,
                                                 const u16* __restrict__ k_ws,
                                                 const u16* __restrict__ v_ws,
                                                 u16* __restrict__ ao) {
  // [kb0 24576][kb1 24576][V 24576][guard 512]
  __shared__ __align__(16) unsigned char lds[74240];
  int wg = blockIdx.x;
  int virt = (wg & 7) * 36 + (wg >> 3);   // XCD-affine: 288 = 8 * 36
  int slice = virt / 18;                  // 0..15
  int qt = virt % 18;                     // 0..17 (128 q each)
  int b = slice >> 3, d = slice & 7;
  int tid = threadIdx.x;
  int lane = tid & 63, w = tid >> 6;
  int l31 = lane & 31, hi = lane >> 5;

  const char* kgb = (const char*)k_ws + (size_t)slice * 1179648;
  const char* vgb = (const char*)v_ws + (size_t)slice * 1179648;

  // hoist Q fragments (32 q per wave; prescaled by softmax-scale*log2e)
  size_t nbase = (size_t)b * ND_ + d * HW_ + qt * 128 + w * 32;
  const char* qp = (const char*)q_ws + (nbase + l31) * 512 + hi * 16;
  short8 qf[16];
#pragma unroll
  for (int ks = 0; ks < 16; ks++) qf[ks] = *(const short8*)(qp + ks * 32);

  f32x16 acc[8];
#pragma unroll
  for (int i = 0; i < 8; i++) acc[i] = (f32x16)0.0f;

  // stage K tile t into kb base_: 256 thr x 16B x 6, linear both sides
#define STG_K(t_, base_) {                                             \
    const char* s_ = kgb + (size_t)(t_) * 24576 + tid * 16;            \
    char* d_ = (char*)lds + (base_) + w * 1024;                        \
    _Pragma("unroll")                                                  \
    for (int i_ = 0; i_ < 6; i_++)                                     \
      gll16(s_ + i_ * 4096, d_ + i_ * 4096);                           \
  }
  // stage V tile t into the single V buffer @49152
#define STG_V(t_) {                                                    \
    const char* s_ = vgb + (size_t)(t_) * 24576 + tid * 16;            \
    char* d_ = (char*)lds + 49152 + w * 1024;                          \
    _Pragma("unroll")                                                  \
    for (int i_ = 0; i_ < 6; i_++)                                     \
      gll16(s_ + i_ * 4096, d_ + i_ * 4096);                           \
  }

  STG_K(0, 0);
  STG_V(0);
  __builtin_amdgcn_sched_barrier(0);
  asm volatile("s_waitcnt vmcnt(0)" ::: "memory");
  __builtin_amdgcn_sched_barrier(0);
  __builtin_amdgcn_s_barrier();

  int kcur = 0;
  for (int t = 0; t < 48; t++) {
    if (t < 47) STG_K(t + 1, (kcur ^ 1) * 24576);   // fire; drains at mid-iter wait

    const char* kb = (const char*)lds + kcur * 24576;
    // two loop-invariant bases; ks offset is a compile-time immediate (<= 23040)
    const char* kb0 = kb + hi * 768 + l31 * 16;
    const char* kb1 = kb + hi * 768 + 512 + (l31 & 15) * 16;

    // QK^T swapped: S[key][q], K fragment-linear: slot*768 + key*16.
    // k1 rows 48..63 (garbage, discarded) aliased onto rows 32..47: broadcast, free.
    f32x16 S0 = (f32x16)0.0f, S1 = (f32x16)0.0f;
#pragma unroll
    for (int ks = 0; ks < 16; ks++) {
      short8 k0 = *(const short8*)(kb0 + ks * 1536);
      short8 k1 = *(const short8*)(kb1 + ks * 1536);
      S0 = __builtin_amdgcn_mfma_f32_32x32x16_bf16(k0, qf[ks], S0, 0, 0, 0);
      S1 = __builtin_amdgcn_mfma_f32_32x32x16_bf16(k1, qf[ks], S1, 0, 0, 0);
    }

    // exact softmax over the 48 keys (one group), lane-local + one half-swap
#pragma unroll
    for (int r = 0; r < 16; r++) S0[r] = __builtin_amdgcn_exp2f(S0[r]);
#pragma unroll
    for (int r = 0; r < 8; r++)  S1[r] = __builtin_amdgcn_exp2f(S1[r]);
    float z = 0.f;
#pragma unroll
    for (int r = 0; r < 16; r++) z += S0[r];
#pragma unroll
    for (int r = 0; r < 8; r++)  z += S1[r];
    z += __shfl_xor(z, 32, 64);
    float inv = __builtin_amdgcn_rcpf(z);
#pragma unroll
    for (int r = 0; r < 16; r++) S0[r] *= inv;
#pragma unroll
    for (int r = 0; r < 8; r++)  S1[r] *= inv;

    // pack P -> PV A-fragments (cvt_pk + permlane32_swap)
    short8 pa[3];
#pragma unroll
    for (int s = 0; s < 3; s++) {
      const f32x16& P = (s < 2) ? S0 : S1;
      const int a = (s == 1) ? 8 : 0;
      u32 u0, u1, v0, v1;
      asm("v_cvt_pk_bf16_f32 %0, %1, %2" : "=v"(u0) : "v"(P[a + 0]), "v"(P[a + 1]));
      asm("v_cvt_pk_bf16_f32 %0, %1, %2" : "=v"(u1) : "v"(P[a + 2]), "v"(P[a + 3]));
      asm("v_cvt_pk_bf16_f32 %0, %1, %2" : "=v"(v0) : "v"(P[a + 4]), "v"(P[a + 5]));
      asm("v_cvt_pk_bf16_f32 %0, %1, %2" : "=v"(v1) : "v"(P[a + 6]), "v"(P[a + 7]));
      asm("v_permlane32_swap_b32 %0, %1" : "+v"(u0), "+v"(v0));
      asm("v_permlane32_swap_b32 %0, %1" : "+v"(u1), "+v"(v1));
      u32x4 wv; wv[0] = u0; wv[1] = u1; wv[2] = v0; wv[3] = v1;
      pa[s] = __builtin_bit_cast(short8, wv);
    }

    // mid sync: K(t+1) and V(t) landed (own loads), then cross-wave barrier
    __builtin_amdgcn_sched_barrier(0);
    asm volatile("s_waitcnt vmcnt(0)" ::: "memory");
    __builtin_amdgcn_sched_barrier(0);
    __builtin_amdgcn_s_barrier();

    // PV from LDS: V fragment-linear: slot*4096 + c*16
    const char* vb = (const char*)lds + 49152;
#pragma unroll
    for (int s = 0; s < 3; s++) {
      const char* vs = vb + (s * 2 + hi) * 4096 + l31 * 16;
#pragma unroll
      for (int ct = 0; ct < 8; ct++) {
        short8 vf = *(const short8*)(vs + ct * 512);
        acc[ct] = __builtin_amdgcn_mfma_f32_32x32x16_bf16(pa[s], vf, acc[ct], 0, 0, 0);
      }
    }

    // all waves done reading V buffer, then refill it for t+1
    __builtin_amdgcn_s_barrier();
    if (t < 47) STG_V(t + 1);
    kcur ^= 1;
  }

  // epilogue: D layout col(l31)=c, row=(r&3)+8*(r>>2)+4*hi = q
#pragma unroll
  for (int ct = 0; ct < 8; ct++) {
#pragma unroll
    for (int r = 0; r < 16; r++) {
      int ql = (r & 3) + 8 * (r >> 2) + 4 * hi;
      ao[(nbase + ql) * 256 + ct * 32 + l31] = f2bf(acc[ct][r]);
    }
  }
}

// ---------------- proj + bias + residual -> d_out f32 channel-major ----------------
__global__ __launch_bounds__(256) void k_proj(const u16* __restrict__ ao,
                                              const u16* __restrict__ w_p,
                                              const float* __restrict__ proj_b,
                                              const float* __restrict__ x,
                                              float* __restrict__ out) {
  int wg = blockIdx.x;
  int nt = wg % 144; int ot = (wg / 144) & 3; int b = wg / 576;
  int n0 = nt * 128, o0 = ot * 64;
  int lane = threadIdx.x & 63; int w = threadIdx.x >> 6;
  int g = lane >> 4, lid = lane & 15;
  int o_w = o0 + w * 16;
  f32x4 acc[8];
#pragma unroll
  for (int t = 0; t < 8; t++) acc[t] = (f32x4){0.f, 0.f, 0.f, 0.f};
  const short8* Ab = (const short8*)(w_p + ((size_t)(o_w + lid)) * C_ + g * 8);
#pragma unroll
  for (int ks = 0; ks < 8; ks++) {
    short8 a = Ab[ks * 4];
#pragma unroll
    for (int t = 0; t < 8; t++) {
      short8 bf = *(const short8*)(ao + ((size_t)(b * ND_ + n0 + t * 16 + lid)) * C_ + ks * 32 + g * 8);
      acc[t] = __builtin_amdgcn_mfma_f32_16x16x32_bf16(a, bf, acc[t], 0, 0, 0);
    }
  }
#pragma unroll
  for (int t = 0; t < 8; t++) {
#pragma unroll
    for (int r = 0; r < 4; r++) {
      int o = o_w + g * 4 + r;
      size_t off = ((size_t)(b * C_ + o)) * ND_ + n0 + t * 16 + lid;
      out[off] = acc[t][r] + proj_b[o] + x[off];
    }
  }
}

extern "C" void kernel_launch(void* const* d_in, const int* in_sizes, int n_in,
                              void* d_out, int out_size, void* d_ws, size_t ws_size,
                              hipStream_t stream) {
  const float* x      = (const float*)d_in[0];
  const float* norm_w = (const float*)d_in[1];
  const float* norm_b = (const float*)d_in[2];
  const float* qkv_w  = (const float*)d_in[3];
  const float* qkv_b  = (const float*)d_in[4];
  const float* proj_w = (const float*)d_in[5];
  const float* proj_b = (const float*)d_in[6];

  char* ws = (char*)d_ws;
  float* stats = (float*)ws;            // f32[128]
  float* raw   = (float*)(ws + 512);    // f32[128] partial accumulators
  u16* w_qkv = (u16*)(ws + 1024);
  u16* w_p   = (u16*)(ws + 1024 + 393216);
  u16* h_t   = (u16*)(ws + 525312);
  u16* q_ws  = h_t + 9437184;
  u16* k_ws  = q_ws + 9437184;
  u16* v_ws  = k_ws + 9437184;
  u16* ao    = h_t;  // alias: h_t dead after k_v
  float* out = (float*)d_out;

  if (ws_size < (size_t)525312 + 4ull * 9437184ull * 2ull) return;

  hipLaunchKernelGGL(k_convert_w, dim3(1024), dim3(256), 0, stream, qkv_w, proj_w, w_qkv, raw);
  hipLaunchKernelGGL(k_gn_part,   dim3(256),  dim3(256), 0, stream, x, raw);
  hipLaunchKernelGGL(k_gn_fin,    dim3(1),    dim3(64),  0, stream, raw, stats);
  hipLaunchKernelGGL(k_tnorm,     dim3(2304), dim3(256), 0, stream, x, stats, norm_w, norm_b, h_t);
  hipLaunchKernelGGL(k_qk,        dim3(2304), dim3(256), 0, stream, h_t, w_qkv, qkv_b, q_ws, k_ws);
  hipLaunchKernelGGL(k_v,         dim3(1152), dim3(256), 0, stream, h_t, w_qkv, qkv_b, v_ws);
  hipLaunchKernelGGL(k_attn,      dim3(288),  dim3(256), 0, stream, q_ws, k_ws, v_ws, ao);
  hipLaunchKernelGGL(k_proj,      dim3(1152), dim3(256), 0, stream, ao, w_p, proj_b, x, out);
}

// Round 16
// 324.700 us; speedup vs baseline: 2.1071x; 1.0299x over previous
//
#include <hip/hip_runtime.h>
#include <hip/hip_bf16.h>

typedef __attribute__((ext_vector_type(8))) short short8;   // 8 bf16
typedef __attribute__((ext_vector_type(4))) float f32x4;
typedef __attribute__((ext_vector_type(16))) float f32x16;
typedef __attribute__((ext_vector_type(4))) unsigned int u32x4;
typedef unsigned int u32;
typedef unsigned short u16;

#define C_ 256
#define G_ 32
#define ND_ 18432          // D*H*W per batch
#define HW_ 2304           // 48*48
#define EPS_ 1e-5f
// (C/8)^-0.5 * log2(e): softmax scale pre-folded with exp2 conversion
#define QS2_ 0.25503487f

static __device__ __forceinline__ u16 f2bf(float f) {
  __hip_bfloat16 h = __float2bfloat16(f);
  return __builtin_bit_cast(u16, h);
}

static __device__ __forceinline__ void gll16(const void* g, void* l) {
  __builtin_amdgcn_global_load_lds(
      (const __attribute__((address_space(1))) unsigned int*)g,
      (__attribute__((address_space(3))) unsigned int*)l, 16, 0, 0);
}

// ---------------- weights f32 -> bf16 (+ zero gn partial accumulators) ----------------
__global__ void k_convert_w(const float* __restrict__ qkv_w,
                            const float* __restrict__ proj_w,
                            u16* __restrict__ wout,
                            float* __restrict__ raw) {
  if (blockIdx.x == 0 && threadIdx.x < 128) raw[threadIdx.x] = 0.f;
  int i = blockIdx.x * 256 + threadIdx.x;   // grid 1024 -> 262144 exactly
  if (i < 196608) wout[i] = f2bf(qkv_w[i]);
  else            wout[i] = f2bf(proj_w[i - 196608]);
}

// ---------------- GroupNorm stats, stage 1: 256 blocks of partial sums ----------------
__global__ __launch_bounds__(256) void k_gn_part(const float* __restrict__ x,
                                                 float* __restrict__ raw) {
  int grp = blockIdx.x >> 2, sub = blockIdx.x & 3;
  const float4* p = (const float4*)(x + (size_t)grp * 147456 + sub * 36864);
  float s1 = 0.f, s2 = 0.f;
  for (int i = threadIdx.x; i < 9216; i += 256) {
    float4 v = p[i];
    s1 += v.x + v.y + v.z + v.w;
    s2 += v.x*v.x + v.y*v.y + v.z*v.z + v.w*v.w;
  }
  for (int off = 1; off < 64; off <<= 1) {
    s1 += __shfl_xor(s1, off, 64);
    s2 += __shfl_xor(s2, off, 64);
  }
  __shared__ float a1[4], a2[4];
  int w = threadIdx.x >> 6;
  if ((threadIdx.x & 63) == 0) { a1[w] = s1; a2[w] = s2; }
  __syncthreads();
  if (threadIdx.x == 0) {
    float t1 = a1[0] + a1[1] + a1[2] + a1[3];
    float t2 = a2[0] + a2[1] + a2[2] + a2[3];
    atomicAdd(&raw[grp * 2], t1);
    atomicAdd(&raw[grp * 2 + 1], t2);
  }
}

// ---------------- GroupNorm stats, stage 2: finalize ----------------
__global__ void k_gn_fin(const float* __restrict__ raw, float* __restrict__ stats) {
  int g = threadIdx.x;
  if (g < 64) {
    float mu  = raw[g * 2] / 147456.0f;
    float var = raw[g * 2 + 1] / 147456.0f - mu * mu;
    stats[g * 2]     = mu;
    stats[g * 2 + 1] = rsqrtf(var + EPS_);
  }
}

// ---------------- normalize + transpose: x[b][c][n] f32 -> h_t[b][n][c] bf16 ----------------
__global__ __launch_bounds__(256) void k_tnorm(const float* __restrict__ x,
                                               const float* __restrict__ stats,
                                               const float* __restrict__ nw,
                                               const float* __restrict__ nb,
                                               u16* __restrict__ h_t) {
  __shared__ u16 tl[64 * 66];
  int wg = blockIdx.x;          // 2304 = b(2) * ct(4) * nt(288)
  int nt = wg % 288; int ct = (wg / 288) & 3; int b = wg / 1152;
  int c0 = ct * 64, n0 = nt * 64;
  int tid = threadIdx.x;
#pragma unroll
  for (int p = 0; p < 4; p++) {
    int c_l = p * 16 + (tid >> 4);
    int n4  = (tid & 15) * 4;
    int cg  = c0 + c_l;
    float4 v = *(const float4*)(x + ((size_t)(b * C_ + cg)) * ND_ + n0 + n4);
    float mu = stats[(b * G_ + (cg >> 3)) * 2];
    float rs = stats[(b * G_ + (cg >> 3)) * 2 + 1];
    float w = nw[cg], bia = nb[cg];
    tl[(n4 + 0) * 66 + c_l] = f2bf((v.x - mu) * rs * w + bia);
    tl[(n4 + 1) * 66 + c_l] = f2bf((v.y - mu) * rs * w + bia);
    tl[(n4 + 2) * 66 + c_l] = f2bf((v.z - mu) * rs * w + bia);
    tl[(n4 + 3) * 66 + c_l] = f2bf((v.w - mu) * rs * w + bia);
  }
  __syncthreads();
#pragma unroll
  for (int p = 0; p < 2; p++) {
    int idx = p * 256 + tid;
    int n_l = idx >> 3, c8 = idx & 7;
    const u32* s = (const u32*)((const char*)tl + n_l * 132 + c8 * 16);
    uint4 vv; vv.x = s[0]; vv.y = s[1]; vv.z = s[2]; vv.w = s[3];
    *(uint4*)(h_t + ((size_t)(b * ND_ + n0 + n_l)) * C_ + c0 + c8 * 8) = vv;
  }
}

// ---------------- QK GEMM (swapped: A=H [n x c], B=W^T [c x o]) ----------------
// Q -> q_ws [b][n][256] (prescaled); K -> k_ws fragment-linear:
// off_u16(slice, t, key, ch) = ((slice*48+t)*1536 + (ch>>3)*48 + key)*8 + (ch&7)
__global__ __launch_bounds__(256) void k_qk(const u16* __restrict__ h_t,
                                            const u16* __restrict__ w_qkv,
                                            const float* __restrict__ qkv_b,
                                            u16* __restrict__ q_ws,
                                            u16* __restrict__ k_ws) {
  int wg = blockIdx.x;
  int nt = wg % 288; int ot = (wg / 288) & 3; int b = wg / 1152;
  int n0 = nt * 64, o0 = ot * 128;
  int lane = threadIdx.x & 63; int w = threadIdx.x >> 6;
  int g = lane >> 4, lid = lane & 15;
  int n_w = n0 + w * 16;
  f32x4 acc[8];
#pragma unroll
  for (int t = 0; t < 8; t++) acc[t] = (f32x4){0.f, 0.f, 0.f, 0.f};
  const short8* Ab = (const short8*)(h_t + ((size_t)(b * ND_ + n_w + lid)) * C_ + g * 8);
#pragma unroll
  for (int ks = 0; ks < 8; ks++) {
    short8 a = Ab[ks * 4];
#pragma unroll
    for (int t = 0; t < 8; t++) {
      short8 bf = *(const short8*)(w_qkv + ((size_t)(o0 + t * 16 + lid)) * C_ + ks * 32 + g * 8);
      acc[t] = __builtin_amdgcn_mfma_f32_16x16x32_bf16(a, bf, acc[t], 0, 0, 0);
    }
  }
  if (o0 < 256) {   // Q path (uniform per block)
#pragma unroll
    for (int t = 0; t < 8; t++) {
      int o_t = o0 + t * 16;
      float bias = qkv_b[o_t + lid];
#pragma unroll
      for (int r = 0; r < 4; r++) {
        int n_idx = n_w + g * 4 + r;
        q_ws[((size_t)(b * ND_ + n_idx)) * C_ + o_t + lid] = f2bf((acc[t][r] + bias) * QS2_);
      }
    }
  } else {          // K path -> fragment-linear layout
#pragma unroll
    for (int t = 0; t < 8; t++) {
      int o_t = o0 + t * 16;
      float bias = qkv_b[o_t + lid];
      int oc = o_t - 256 + lid;
#pragma unroll
      for (int r = 0; r < 4; r++) {
        int n_idx = n_w + g * 4 + r;
        int dd = n_idx / 2304, hw = n_idx % 2304;
        int tt = hw / 48, kk = hw % 48;
        size_t off = ((size_t)((b * 8 + dd) * 48 + tt) * 1536 + (oc >> 3) * 48 + kk) * 8 + (oc & 7);
        k_ws[off] = f2bf(acc[t][r] + bias);
      }
    }
  }
}

// ---------------- V GEMM -> v_ws group-major [slice][grp48][slot6][c256][8] ----------------
__global__ __launch_bounds__(256) void k_v(const u16* __restrict__ h_t,
                                           const u16* __restrict__ w_qkv,
                                           const float* __restrict__ qkv_b,
                                           u16* __restrict__ v_ws) {
  int wg = blockIdx.x;
  int nt = wg % 144; int ot = (wg / 144) & 3; int b = wg / 576;
  int n0 = nt * 128, o0 = ot * 64;
  int lane = threadIdx.x & 63; int w = threadIdx.x >> 6;
  int g = lane >> 4, lid = lane & 15;
  int o_w = o0 + w * 16;
  f32x4 acc[8];
#pragma unroll
  for (int t = 0; t < 8; t++) acc[t] = (f32x4){0.f, 0.f, 0.f, 0.f};
  const short8* Ab = (const short8*)(w_qkv + ((size_t)(512 + o_w + lid)) * C_ + g * 8);
#pragma unroll
  for (int ks = 0; ks < 8; ks++) {
    short8 a = Ab[ks * 4];
#pragma unroll
    for (int t = 0; t < 8; t++) {
      short8 bf = *(const short8*)(h_t + ((size_t)(b * ND_ + n0 + t * 16 + lid)) * C_ + ks * 32 + g * 8);
      acc[t] = __builtin_amdgcn_mfma_f32_16x16x32_bf16(a, bf, acc[t], 0, 0, 0);
    }
  }
#pragma unroll
  for (int t = 0; t < 8; t++) {
#pragma unroll
    for (int r = 0; r < 4; r++) {
      int o = o_w + g * 4 + r;
      int n = n0 + t * 16 + lid;
      int d = n / 2304; int hw = n % 2304;
      int grp = hw / 48; int j = hw % 48;
      size_t idx = ((size_t)(((b * 8 + d) * 48 + grp) * 6 + (j >> 3))) * 2048 + o * 8 + (j & 7);
      v_ws[idx] = f2bf(acc[t][r] + qkv_b[512 + o]);
    }
  }
}

// ---------------- fused attention: 192 blocks x 6 waves x 32q (192 q / block) ----------
// R8/R15 per-wave code unchanged; repackaged so EVERY block gets its own CU:
// grid 192 <= 256, LDS padded to 84.5KB -> 1 block/CU, no doubled CUs, no tail.
// 6 waves share the K dbuf + V buffer (1.5 waves/SIMD). 384 threads stage.
// Schedule: STG_K(t+1) -> QK -> softmax -> vmcnt(0)+bar -> PV -> bar -> STG_V(t+1).
__global__ __launch_bounds__(384, 1) void k_attn(const u16* __restrict__ q_ws,
                                                 const u16* __restrict__ k_ws,
                                                 const u16* __restrict__ v_ws,
                                                 u16* __restrict__ ao) {
  // [kb0 24576][kb1 24576][V 24576][pad to 84480 > 80KB => 1 block/CU]
  __shared__ __align__(16) unsigned char lds[84480];
  int wg = blockIdx.x;
  int virt = (wg & 7) * 24 + (wg >> 3);   // XCD-affine: 192 = 8 * 24
  int slice = virt / 12;                  // 0..15
  int qt = virt % 12;                     // 0..11 (192 q each)
  int b = slice >> 3, d = slice & 7;
  int tid = threadIdx.x;
  int lane = tid & 63, w = tid >> 6;      // w 0..5
  int l31 = lane & 31, hi = lane >> 5;

  const char* kgb = (const char*)k_ws + (size_t)slice * 1179648;
  const char* vgb = (const char*)v_ws + (size_t)slice * 1179648;

  // hoist Q fragments (32 q per wave; prescaled by softmax-scale*log2e)
  size_t nbase = (size_t)b * ND_ + d * HW_ + qt * 192 + w * 32;
  const char* qp = (const char*)q_ws + (nbase + l31) * 512 + hi * 16;
  short8 qf[16];
#pragma unroll
  for (int ks = 0; ks < 16; ks++) qf[ks] = *(const short8*)(qp + ks * 32);

  f32x16 acc[8];
#pragma unroll
  for (int i = 0; i < 8; i++) acc[i] = (f32x16)0.0f;

  // stage K tile t into kb base_: 384 thr x 16B x 4, linear both sides
#define STG_K(t_, base_) {                                             \
    const char* s_ = kgb + (size_t)(t_) * 24576 + tid * 16;            \
    char* d_ = (char*)lds + (base_) + tid * 16;                        \
    _Pragma("unroll")                                                  \
    for (int i_ = 0; i_ < 4; i_++)                                     \
      gll16(s_ + i_ * 6144, d_ + i_ * 6144);                           \
  }
  // stage V tile t into the single V buffer @49152
#define STG_V(t_) {                                                    \
    const char* s_ = vgb + (size_t)(t_) * 24576 + tid * 16;            \
    char* d_ = (char*)lds + 49152 + tid * 16;                          \
    _Pragma("unroll")                                                  \
    for (int i_ = 0; i_ < 4; i_++)                                     \
      gll16(s_ + i_ * 6144, d_ + i_ * 6144);                           \
  }

  STG_K(0, 0);
  STG_V(0);
  __builtin_amdgcn_sched_barrier(0);
  asm volatile("s_waitcnt vmcnt(0)" ::: "memory");
  __builtin_amdgcn_sched_barrier(0);
  __builtin_amdgcn_s_barrier();

  int kcur = 0;
  for (int t = 0; t < 48; t++) {
    if (t < 47) STG_K(t + 1, (kcur ^ 1) * 24576);   // fire; drains at mid-iter wait

    const char* kb = (const char*)lds + kcur * 24576;
    // two loop-invariant bases; ks offset is a compile-time immediate (<= 23040)
    const char* kb0 = kb + hi * 768 + l31 * 16;
    const char* kb1 = kb + hi * 768 + 512 + (l31 & 15) * 16;

    // QK^T swapped: S[key][q], K fragment-linear: slot*768 + key*16.
    f32x16 S0 = (f32x16)0.0f, S1 = (f32x16)0.0f;
#pragma unroll
    for (int ks = 0; ks < 16; ks++) {
      short8 k0 = *(const short8*)(kb0 + ks * 1536);
      short8 k1 = *(const short8*)(kb1 + ks * 1536);
      S0 = __builtin_amdgcn_mfma_f32_32x32x16_bf16(k0, qf[ks], S0, 0, 0, 0);
      S1 = __builtin_amdgcn_mfma_f32_32x32x16_bf16(k1, qf[ks], S1, 0, 0, 0);
    }

    // exact softmax over the 48 keys (one group), lane-local + one half-swap
#pragma unroll
    for (int r = 0; r < 16; r++) S0[r] = __builtin_amdgcn_exp2f(S0[r]);
#pragma unroll
    for (int r = 0; r < 8; r++)  S1[r] = __builtin_amdgcn_exp2f(S1[r]);
    float z = 0.f;
#pragma unroll
    for (int r = 0; r < 16; r++) z += S0[r];
#pragma unroll
    for (int r = 0; r < 8; r++)  z += S1[r];
    z += __shfl_xor(z, 32, 64);
    float inv = __builtin_amdgcn_rcpf(z);
#pragma unroll
    for (int r = 0; r < 16; r++) S0[r] *= inv;
#pragma unroll
    for (int r = 0; r < 8; r++)  S1[r] *= inv;

    // pack P -> PV A-fragments (cvt_pk + permlane32_swap)
    short8 pa[3];
#pragma unroll
    for (int s = 0; s < 3; s++) {
      const f32x16& P = (s < 2) ? S0 : S1;
      const int a = (s == 1) ? 8 : 0;
      u32 u0, u1, v0, v1;
      asm("v_cvt_pk_bf16_f32 %0, %1, %2" : "=v"(u0) : "v"(P[a + 0]), "v"(P[a + 1]));
      asm("v_cvt_pk_bf16_f32 %0, %1, %2" : "=v"(u1) : "v"(P[a + 2]), "v"(P[a + 3]));
      asm("v_cvt_pk_bf16_f32 %0, %1, %2" : "=v"(v0) : "v"(P[a + 4]), "v"(P[a + 5]));
      asm("v_cvt_pk_bf16_f32 %0, %1, %2" : "=v"(v1) : "v"(P[a + 6]), "v"(P[a + 7]));
      asm("v_permlane32_swap_b32 %0, %1" : "+v"(u0), "+v"(v0));
      asm("v_permlane32_swap_b32 %0, %1" : "+v"(u1), "+v"(v1));
      u32x4 wv; wv[0] = u0; wv[1] = u1; wv[2] = v0; wv[3] = v1;
      pa[s] = __builtin_bit_cast(short8, wv);
    }

    // mid sync: K(t+1) and V(t) landed (own loads), then cross-wave barrier
    __builtin_amdgcn_sched_barrier(0);
    asm volatile("s_waitcnt vmcnt(0)" ::: "memory");
    __builtin_amdgcn_sched_barrier(0);
    __builtin_amdgcn_s_barrier();

    // PV from LDS: V fragment-linear: slot*4096 + c*16
    const char* vb = (const char*)lds + 49152;
#pragma unroll
    for (int s = 0; s < 3; s++) {
      const char* vs = vb + (s * 2 + hi) * 4096 + l31 * 16;
#pragma unroll
      for (int ct = 0; ct < 8; ct++) {
        short8 vf = *(const short8*)(vs + ct * 512);
        acc[ct] = __builtin_amdgcn_mfma_f32_32x32x16_bf16(pa[s], vf, acc[ct], 0, 0, 0);
      }
    }

    // all waves done reading V buffer, then refill it for t+1
    __builtin_amdgcn_s_barrier();
    if (t < 47) STG_V(t + 1);
    kcur ^= 1;
  }

  // epilogue: D layout col(l31)=c, row=(r&3)+8*(r>>2)+4*hi = q
#pragma unroll
  for (int ct = 0; ct < 8; ct++) {
#pragma unroll
    for (int r = 0; r < 16; r++) {
      int ql = (r & 3) + 8 * (r >> 2) + 4 * hi;
      ao[(nbase + ql) * 256 + ct * 32 + l31] = f2bf(acc[ct][r]);
    }
  }
}

// ---------------- proj + bias + residual -> d_out f32 channel-major ----------------
__global__ __launch_bounds__(256) void k_proj(const u16* __restrict__ ao,
                                              const u16* __restrict__ w_p,
                                              const float* __restrict__ proj_b,
                                              const float* __restrict__ x,
                                              float* __restrict__ out) {
  int wg = blockIdx.x;
  int nt = wg % 144; int ot = (wg / 144) & 3; int b = wg / 576;
  int n0 = nt * 128, o0 = ot * 64;
  int lane = threadIdx.x & 63; int w = threadIdx.x >> 6;
  int g = lane >> 4, lid = lane & 15;
  int o_w = o0 + w * 16;
  f32x4 acc[8];
#pragma unroll
  for (int t = 0; t < 8; t++) acc[t] = (f32x4){0.f, 0.f, 0.f, 0.f};
  const short8* Ab = (const short8*)(w_p + ((size_t)(o_w + lid)) * C_ + g * 8);
#pragma unroll
  for (int ks = 0; ks < 8; ks++) {
    short8 a = Ab[ks * 4];
#pragma unroll
    for (int t = 0; t < 8; t++) {
      short8 bf = *(const short8*)(ao + ((size_t)(b * ND_ + n0 + t * 16 + lid)) * C_ + ks * 32 + g * 8);
      acc[t] = __builtin_amdgcn_mfma_f32_16x16x32_bf16(a, bf, acc[t], 0, 0, 0);
    }
  }
#pragma unroll
  for (int t = 0; t < 8; t++) {
#pragma unroll
    for (int r = 0; r < 4; r++) {
      int o = o_w + g * 4 + r;
      size_t off = ((size_t)(b * C_ + o)) * ND_ + n0 + t * 16 + lid;
      out[off] = acc[t][r] + proj_b[o] + x[off];
    }
  }
}

extern "C" void kernel_launch(void* const* d_in, const int* in_sizes, int n_in,
                              void* d_out, int out_size, void* d_ws, size_t ws_size,
                              hipStream_t stream) {
  const float* x      = (const float*)d_in[0];
  const float* norm_w = (const float*)d_in[1];
  const float* norm_b = (const float*)d_in[2];
  const float* qkv_w  = (const float*)d_in[3];
  const float* qkv_b  = (const float*)d_in[4];
  const float* proj_w = (const float*)d_in[5];
  const float* proj_b = (const float*)d_in[6];

  char* ws = (char*)d_ws;
  float* stats = (float*)ws;            // f32[128]
  float* raw   = (float*)(ws + 512);    // f32[128] partial accumulators
  u16* w_qkv = (u16*)(ws + 1024);
  u16* w_p   = (u16*)(ws + 1024 + 393216);
  u16* h_t   = (u16*)(ws + 525312);
  u16* q_ws  = h_t + 9437184;
  u16* k_ws  = q_ws + 9437184;
  u16* v_ws  = k_ws + 9437184;
  u16* ao    = h_t;  // alias: h_t dead after k_v
  float* out = (float*)d_out;

  if (ws_size < (size_t)525312 + 4ull * 9437184ull * 2ull) return;

  hipLaunchKernelGGL(k_convert_w, dim3(1024), dim3(256), 0, stream, qkv_w, proj_w, w_qkv, raw);
  hipLaunchKernelGGL(k_gn_part,   dim3(256),  dim3(256), 0, stream, x, raw);
  hipLaunchKernelGGL(k_gn_fin,    dim3(1),    dim3(64),  0, stream, raw, stats);
  hipLaunchKernelGGL(k_tnorm,     dim3(2304), dim3(256), 0, stream, x, stats, norm_w, norm_b, h_t);
  hipLaunchKernelGGL(k_qk,        dim3(2304), dim3(256), 0, stream, h_t, w_qkv, qkv_b, q_ws, k_ws);
  hipLaunchKernelGGL(k_v,         dim3(1152), dim3(256), 0, stream, h_t, w_qkv, qkv_b, v_ws);
  hipLaunchKernelGGL(k_attn,      dim3(192),  dim3(384), 0, stream, q_ws, k_ws, v_ws, ao);
  hipLaunchKernelGGL(k_proj,      dim3(1152), dim3(256), 0, stream, ao, w_p, proj_b, x, out);
}